// Round 16
// baseline (360.854 us; speedup 1.0000x reference)
//
#include <hip/hip_runtime.h>

typedef __attribute__((ext_vector_type(4))) float f32x4;
typedef __attribute__((ext_vector_type(16))) float f32x16;
typedef __attribute__((ext_vector_type(8))) short bf16x8;
typedef unsigned long long u64;
typedef unsigned short u16;
typedef unsigned int u32;

// round-to-nearest-even f32 -> bf16 bits
static __device__ __forceinline__ u16 f2bf(float f) {
    u32 u = __float_as_uint(f);
    u += 0x7fffu + ((u >> 16) & 1u);
    return (u16)(u >> 16);
}

// ---------------- kernel 1: s[g][ic] = style[g] . mod_w[ic] + mod_b[ic] ----
__global__ void k_style(const float* __restrict__ style, const float* __restrict__ mod_w,
                        const float* __restrict__ mod_b, float* __restrict__ s_ws) {
    int t = blockIdx.x * 256 + threadIdx.x;     // 0..2047
    int g = t >> 9, ic = t & 511;
    const f32x4* st = (const f32x4*)(style + (g << 9));
    const f32x4* mw = (const f32x4*)(mod_w + (ic << 9));
    float acc = 0.f;
#pragma unroll 4
    for (int d = 0; d < 128; ++d) {
        f32x4 a = st[d], b = mw[d];
        acc += a[0]*b[0] + a[1]*b[1] + a[2]*b[2] + a[3]*b[3];
    }
    s_ws[t] = acc + mod_b[ic];
}

// ---------------- kernel 2: Wmod bf16, 32x32 fragment-lane order ----------
// Layout: [g(4)][ocb(4)][wr(2)][ch(16)][tap(9)][kk(2)][oh(2)][lane(64)][e(8)]
// oc = ocb*128 + wr*64 + oh*32 + (lane&31) ; ic = ch*32 + kk*16 + (lane>>5)*8 + e
__global__ void k_wmod(const float* __restrict__ weight, const float* __restrict__ demod,
                       const float* __restrict__ s_ws, short* __restrict__ wmod) {
    int t = blockIdx.x * 256 + threadIdx.x;     // [0, 262144)
    int lane = t & 63; int r = t >> 6;
    int oh = r & 1; r >>= 1;
    int kk = r & 1; r >>= 1;
    int ch = r & 15; r >>= 4;
    int wr = r & 1; r >>= 1;
    int ocb = r & 3; r >>= 2;
    int g = r & 3;
    int oc  = ocb*128 + wr*64 + oh*32 + (lane & 31);
    int ic0 = ch*32 + kk*16 + (lane >> 5)*8;
    const float* wp = weight + (size_t)(oc*512 + ic0)*9;   // 72 contiguous floats
    float sv[8];
#pragma unroll
    for (int e = 0; e < 8; ++e) sv[e] = s_ws[(g << 9) + ic0 + e] * demod[ic0 + e];
    short* base = wmod + ((size_t)((g*4 + ocb)*2 + wr)) * 294912
                + (((kk << 1) + oh) << 9) + (lane << 3);
#pragma unroll
    for (int tp = 0; tp < 9; ++tp) {
        bf16x8 pk;
#pragma unroll
        for (int e = 0; e < 8; ++e) pk[e] = (short)f2bf(wp[e*9 + tp] * sv[e]);
        *(bf16x8*)&base[(size_t)(ch*9 + tp) << 11] = pk;
    }
}

// ---------------- kernel 2b: x fp32 NCHW -> bf16 swizzled [ch][px][k][e] ---
// Zero-LDS pure stream (R15, proven): each thread builds one 16B output
// (8 consecutive ic at one px) from 8 coalesced global loads.
__global__ __launch_bounds__(256) void k_xcast(const float* __restrict__ x,
                                               short* __restrict__ xb) {
    int o = blockIdx.x * 256 + threadIdx.x;     // [0, 1<<22)
    int k  = o & 3, px = (o >> 2) & 63, ch = (o >> 8) & 15;
    int y  = (o >> 12) & 63, g = (o >> 18) & 3, nb = o >> 20;
    int ic0 = ch * 32 + ((k ^ ((px >> 1) & 3)) << 3);
    const float* src = x + (((size_t)(nb * 2048 + (g << 9) + ic0)) << 12) + (y << 6) + px;
    bf16x8 pk;
#pragma unroll
    for (int e = 0; e < 8; ++e)
        pk[e] = (short)f2bf(src[(size_t)e << 12]);
    ((bf16x8*)xb)[o] = pk;
}

// ---------------- kernel 3: main implicit-GEMM conv (32x32x16 MFMA) --------
// R8 retry with the spill fixed: __launch_bounds__(256,3) (R8's (256,4)
// forced VGPR=64 -> 16 MB scratch spill, visible as WRITE=147MB; natural
// need ~95 arch + 64 acc fits the 170-reg budget at 3 waves/SIMD).
// Block 128oc x 128px (2 rows), 4 waves (wr2 x wc2), each 64oc x 64px
// (acc 2x2 x f32x16 = 64 AGPR). BK=32, 16 chunks. Per tap: 4 A-frags
// (global->reg depth-1), 4 B ds_read_b128, 8 MFMA 32x32x16 (chain depth 2,
// 3 independent between). A: row=lane&31, k=(lane>>5)*8+j. B: col=lane&31.
// C/D: col=lane&31, row=(r&3)+8*(r>>2)+4*(lane>>5) [m74/m101; passed R8].
// Barrier = s_waitcnt vmcnt(4) + s_barrier; setprio on MFMA.
// Slot map: pixel x at slot 1+x (slots 0/65 zero halo pads).
__global__ __launch_bounds__(256, 3) void k_conv(const short* __restrict__ xb,
                                                 const short* __restrict__ wmod,
                                                 float* __restrict__ out) {
    __shared__ __align__(16) short Xs[2 * 8448];   // 33792 B -> 3 blocks/CU

    const int tid  = threadIdx.x;
    const int lane = tid & 63;
    const int wv   = tid >> 6;
    const int wr   = wv >> 1, wc = wv & 1;
    const int l31  = lane & 31;
    const int lh   = lane >> 5;
    const int ocb  = blockIdx.x >> 5, rowb = blockIdx.x & 31;
    const int g    = blockIdx.y, nb = blockIdx.z;
    const int y0   = rowb << 1;

    const short* xbg = xb + ((size_t)((nb * 4 + g) * 64) << 15);
    const short* wg  = wmod + ((size_t)((g * 4 + ocb) * 2 + wr)) * 294912;
    float* outg = out + (((size_t)(nb * 2048 + (g << 9) + ocb * 128)) << 12) + (rowb << 7);

    // staging: this wave stages image row gy = y0-1+wv
    const int gy = y0 - 1 + wv;
    const bool srow = (gy >= 0 && gy <= 63);
    const short* xsrc = xbg + ((size_t)(srow ? gy : 0) << 15) + (lane << 3);
    short* xdst0 = Xs + ((wv * 66 + 1) << 5);

    // W pipeline: per-lane pointer, imm offsets 0/512/1024/1536 shorts.
    // No end-clamp: 1-tap over-read lands in xbuf ws memory (never consumed).
    const short* wp = wg + (lane << 3);

    // zero both buffers (pad slots + out-of-range halo rows stay 0 forever)
    for (int i = tid; i < 4224; i += 256) ((u64*)Xs)[i] = 0ull;

    f32x16 acc[2][2];
#pragma unroll
    for (int oh = 0; oh < 2; ++oh)
#pragma unroll
        for (int ph = 0; ph < 2; ++ph)
#pragma unroll
            for (int r = 0; r < 16; ++r) acc[oh][ph][r] = 0.f;

    __syncthreads();                    // zeros visible before any gload_lds lands

    // prologue: stage chunk 0 -> buf 0 (oldest in vmcnt), W tap-0 prefetch
    if (srow) {
#pragma unroll
        for (int q = 0; q < 4; ++q)
            __builtin_amdgcn_global_load_lds(
                (const __attribute__((address_space(1))) void*)(xsrc + (q << 9)),
                (__attribute__((address_space(3))) void*)(xdst0 + (q << 9)), 16, 0, 0);
    }
    __builtin_amdgcn_sched_barrier(0);
    bf16x8 na0 = *(const bf16x8*)(wp);          // kk0,oh0
    bf16x8 na1 = *(const bf16x8*)(wp + 512);    // kk0,oh1
    bf16x8 na2 = *(const bf16x8*)(wp + 1024);   // kk1,oh0
    bf16x8 na3 = *(const bf16x8*)(wp + 1536);   // kk1,oh1
    wp += 2048;

#pragma unroll 1
    for (int ch = 0; ch < 16; ++ch) {
        // T4 barrier: all but the 4 newest (next tap's W) have landed
        asm volatile("s_waitcnt vmcnt(4)" ::: "memory");
        __builtin_amdgcn_s_barrier();
        __builtin_amdgcn_sched_barrier(0);
        if (ch < 15 && srow) {          // stage next chunk into other buffer
            const short* s = xsrc + ((size_t)(ch + 1) << 11);
            short* d = xdst0 + (((ch + 1) & 1) ? 8448 : 0);
#pragma unroll
            for (int q = 0; q < 4; ++q)
                __builtin_amdgcn_global_load_lds(
                    (const __attribute__((address_space(1))) void*)(s + (q << 9)),
                    (__attribute__((address_space(3))) void*)(d + (q << 9)), 16, 0, 0);
        }
        __builtin_amdgcn_sched_barrier(0);   // pin stage issue before tap work
        const int bb = (ch & 1) * 8448;

        // per-dx base LDS offsets at dy=-1 (buffer row = wc): x_read = l31+dx
        // at slot 1+x_read; physical k = (kk*2+lh) ^ ((x_read>>1)&3); kk=0
        // here, kk=1 column = base ^ 16 shorts (kq bit1 flip).
        int pB[3];
#pragma unroll
        for (int d = 0; d < 3; ++d) {
            const int xr = l31 + d - 1;
            pB[d] = bb + ((wc * 66 + 1 + xr) << 5) + ((lh ^ ((xr >> 1) & 3)) << 3);
        }

#pragma unroll
        for (int tap = 0; tap < 9; ++tap) {
            bf16x8 ca0 = na0, ca1 = na1, ca2 = na2, ca3 = na3;
            na0 = *(const bf16x8*)(wp);
            na1 = *(const bf16x8*)(wp + 512);
            na2 = *(const bf16x8*)(wp + 1024);
            na3 = *(const bf16x8*)(wp + 1536);
            wp += 2048;

            const int p0 = pB[tap % 3] + (tap / 3) * 2112;   // kk0, ph0
            const int p1 = p0 ^ 16;                          // kk1 column
            bf16x8 b00 = *(const bf16x8*)&Xs[p0];
            bf16x8 b01 = *(const bf16x8*)&Xs[p0 + 1024];     // ph1: +32 slots
            bf16x8 b10 = *(const bf16x8*)&Xs[p1];
            bf16x8 b11 = *(const bf16x8*)&Xs[p1 + 1024];

            __builtin_amdgcn_s_setprio(1);
            acc[0][0] = __builtin_amdgcn_mfma_f32_32x32x16_bf16(ca0, b00, acc[0][0], 0, 0, 0);
            acc[0][1] = __builtin_amdgcn_mfma_f32_32x32x16_bf16(ca0, b01, acc[0][1], 0, 0, 0);
            acc[1][0] = __builtin_amdgcn_mfma_f32_32x32x16_bf16(ca1, b00, acc[1][0], 0, 0, 0);
            acc[1][1] = __builtin_amdgcn_mfma_f32_32x32x16_bf16(ca1, b01, acc[1][1], 0, 0, 0);
            acc[0][0] = __builtin_amdgcn_mfma_f32_32x32x16_bf16(ca2, b10, acc[0][0], 0, 0, 0);
            acc[0][1] = __builtin_amdgcn_mfma_f32_32x32x16_bf16(ca2, b11, acc[0][1], 0, 0, 0);
            acc[1][0] = __builtin_amdgcn_mfma_f32_32x32x16_bf16(ca3, b10, acc[1][0], 0, 0, 0);
            acc[1][1] = __builtin_amdgcn_mfma_f32_32x32x16_bf16(ca3, b11, acc[1][1], 0, 0, 0);
            __builtin_amdgcn_s_setprio(0);
        }
    }

    // ---- epilogue: C/D col=lane&31 (px), row=(r&3)+8*(r>>2)+4*lh (oc) ----
#pragma unroll
    for (int oh = 0; oh < 2; ++oh)
#pragma unroll
        for (int ph = 0; ph < 2; ++ph) {
            float* dst = outg + ((size_t)((wr << 6) + (oh << 5) + (lh << 2)) << 12)
                       + (wc << 6) + (ph << 5) + l31;
#pragma unroll
            for (int r = 0; r < 16; ++r)
                dst[(size_t)(((r & 3) + ((r >> 2) << 3)) << 12)] = acc[oh][ph][r];
        }
}

extern "C" void kernel_launch(void* const* d_in, const int* in_sizes, int n_in,
                              void* d_out, int out_size, void* d_ws, size_t ws_size,
                              hipStream_t stream) {
    const float* x      = (const float*)d_in[0];
    const float* style  = (const float*)d_in[1];
    const float* weight = (const float*)d_in[2];
    const float* demod  = (const float*)d_in[3];
    const float* mod_w  = (const float*)d_in[4];
    const float* mod_b  = (const float*)d_in[5];
    float* out = (float*)d_out;

    float* s_ws = (float*)d_ws;                           // 8 KB
    short* wmod = (short*)((char*)d_ws + 8192);           // 18.9 MB
    short* xbuf = (short*)((char*)d_ws + 8192 + 18874368);// 67.1 MB (total ~86 MB)

    hipLaunchKernelGGL(k_style, dim3(8), dim3(256), 0, stream, style, mod_w, mod_b, s_ws);
    hipLaunchKernelGGL(k_wmod, dim3(1024), dim3(256), 0, stream, weight, demod, s_ws, wmod);
    hipLaunchKernelGGL(k_xcast, dim3(16384), dim3(256), 0, stream, x, xbuf);
    hipLaunchKernelGGL(k_conv, dim3(128, 4, 4), dim3(256), 0, stream, xbuf, wmod, out);
}

// Round 17
// 305.590 us; speedup vs baseline: 1.1808x; 1.1808x over previous
//
#include <hip/hip_runtime.h>

typedef __attribute__((ext_vector_type(4))) float f32x4;
typedef __attribute__((ext_vector_type(8))) short bf16x8;
typedef unsigned long long u64;
typedef unsigned short u16;
typedef unsigned int u32;

// round-to-nearest-even f32 -> bf16 bits
static __device__ __forceinline__ u16 f2bf(float f) {
    u32 u = __float_as_uint(f);
    u += 0x7fffu + ((u >> 16) & 1u);
    return (u16)(u >> 16);
}

// ---------------- kernel 1: s[g][ic] = style[g] . mod_w[ic] + mod_b[ic] ----
__global__ void k_style(const float* __restrict__ style, const float* __restrict__ mod_w,
                        const float* __restrict__ mod_b, float* __restrict__ s_ws) {
    int t = blockIdx.x * 256 + threadIdx.x;     // 0..2047
    int g = t >> 9, ic = t & 511;
    const f32x4* st = (const f32x4*)(style + (g << 9));
    const f32x4* mw = (const f32x4*)(mod_w + (ic << 9));
    float acc = 0.f;
#pragma unroll 4
    for (int d = 0; d < 128; ++d) {
        f32x4 a = st[d], b = mw[d];
        acc += a[0]*b[0] + a[1]*b[1] + a[2]*b[2] + a[3]*b[3];
    }
    s_ws[t] = acc + mod_b[ic];
}

// ---------------- kernel 2: Wmod bf16, 16x16 fragment-lane order ----------
// Layout: [g(4)][ocb(4)][wr(2)][ch(16)][tap(9)][m(4)][lane(64)][e(8)]
// oc = ocb*128 + wr*64 + m*16 + (lane&15) ; ic = ch*32 + (lane>>4)*8 + e
__global__ void k_wmod(const float* __restrict__ weight, const float* __restrict__ demod,
                       const float* __restrict__ s_ws, short* __restrict__ wmod) {
    int t = blockIdx.x * 256 + threadIdx.x;     // [0, 131072)
    int lane = t & 63; int r = t >> 6;
    int m = r & 3; r >>= 2;
    int ch = r & 15; r >>= 4;
    int wr = r & 1; r >>= 1;
    int ocb = r & 3; r >>= 2;
    int g = r & 3;
    int oc  = ocb*128 + wr*64 + m*16 + (lane & 15);
    int ic0 = ch*32 + (lane >> 4)*8;
    const float* wp = weight + (size_t)(oc*512 + ic0)*9;   // 72 contiguous floats
    float sv[8];
#pragma unroll
    for (int e = 0; e < 8; ++e) sv[e] = s_ws[(g << 9) + ic0 + e] * demod[ic0 + e];
    short* base = wmod + ((size_t)((g*4 + ocb)*2 + wr)) * 294912 + ((size_t)m << 9) + (lane << 3);
#pragma unroll
    for (int tp = 0; tp < 9; ++tp) {
        bf16x8 pk;
#pragma unroll
        for (int e = 0; e < 8; ++e) pk[e] = (short)f2bf(wp[e*9 + tp] * sv[e]);
        *(bf16x8*)&base[(size_t)(ch*9 + tp) << 11] = pk;
    }
}

// ---------------- kernel 2b: x fp32 NCHW -> bf16 swizzled [ch][px][k][e] ---
// Zero-LDS pure stream (R15, proven): each thread builds one 16B output
// (8 consecutive ic at one px) from 8 coalesced global loads.
__global__ __launch_bounds__(256) void k_xcast(const float* __restrict__ x,
                                               short* __restrict__ xb) {
    int o = blockIdx.x * 256 + threadIdx.x;     // [0, 1<<22)
    int k  = o & 3, px = (o >> 2) & 63, ch = (o >> 8) & 15;
    int y  = (o >> 12) & 63, g = (o >> 18) & 3, nb = o >> 20;
    int ic0 = ch * 32 + ((k ^ ((px >> 1) & 3)) << 3);
    const float* src = x + (((size_t)(nb * 2048 + (g << 9) + ic0)) << 12) + (y << 6) + px;
    bf16x8 pk;
#pragma unroll
    for (int e = 0; e < 8; ++e)
        pk[e] = (short)f2bf(src[(size_t)e << 12]);
    ((bf16x8*)xb)[o] = pk;
}

// ---------------- kernel 3: main conv body (templated tap rotation) --------
// R11/R15 engine (proven: MfmaUtil 65, conflicts 0, WRITE exact) with
// per-block TAP-ORDER ROTATION: co-resident blocks ((linear>>8)&1
// alternates) run taps OFF..OFF+8 mod 9 -> per-tap stall slivers and
// barrier-head serial sections decorrelate across the blocks sharing a CU,
// while chunk order stays lockstep (preserves W L2 locality — the R12
// confound). Taps are accumulation-order-free. All tap indices are
// compile-time (template OFF + full unroll) -> same inner code quality.
template<int OFF>
static __device__ __forceinline__ void conv_main(
        short* __restrict__ Xs, const short* __restrict__ xsrc,
        short* __restrict__ xdst0, bool srow, const short* __restrict__ wl,
        float* __restrict__ outg, int wc, int wr, int l15, int l4) {
    f32x4 acc[4][4];
#pragma unroll
    for (int m = 0; m < 4; ++m)
#pragma unroll
        for (int nn = 0; nn < 4; ++nn) acc[m][nn] = (f32x4){0.f, 0.f, 0.f, 0.f};

    __syncthreads();                    // zeros visible before any gload_lds lands

    // prologue: stage chunk 0 -> buf 0 (oldest in vmcnt), W seq[0] prefetch
    if (srow) {
#pragma unroll
        for (int q = 0; q < 4; ++q)
            __builtin_amdgcn_global_load_lds(
                (const __attribute__((address_space(1))) void*)(xsrc + (q << 9)),
                (__attribute__((address_space(3))) void*)(xdst0 + (q << 9)), 16, 0, 0);
    }
    __builtin_amdgcn_sched_barrier(0);
    const short* w0 = wl + OFF * 2048;
    bf16x8 na0 = *(const bf16x8*)(w0);
    bf16x8 na1 = *(const bf16x8*)(w0 + 512);
    bf16x8 na2 = *(const bf16x8*)(w0 + 1024);
    bf16x8 na3 = *(const bf16x8*)(w0 + 1536);

#pragma unroll 1
    for (int ch = 0; ch < 16; ++ch) {
        // T4 barrier: all but the 4 newest (next tap's W) have landed
        asm volatile("s_waitcnt vmcnt(4)" ::: "memory");
        __builtin_amdgcn_s_barrier();
        __builtin_amdgcn_sched_barrier(0);
        if (ch < 15 && srow) {          // stage next chunk into other buffer
            const short* s = xsrc + ((size_t)(ch + 1) << 11);
            short* d = xdst0 + (((ch + 1) & 1) ? 8448 : 0);
#pragma unroll
            for (int q = 0; q < 4; ++q)
                __builtin_amdgcn_global_load_lds(
                    (const __attribute__((address_space(1))) void*)(s + (q << 9)),
                    (__attribute__((address_space(3))) void*)(d + (q << 9)), 16, 0, 0);
        }
        __builtin_amdgcn_sched_barrier(0);   // pin stage issue before tap work
        const int bb = (ch & 1) * 8448;
        const short* wcur = wl + ch * 18432;
        const short* wnxt = wcur + 18432;    // ch=15 over-read lands in ws (unused)

        // per-dx B base offsets at dy=-1 (buffer row = wc); per tap add
        // (dy+1)*2112 shorts. Swizzle: physical k = l4 ^ (((l15+dx)>>1)&3).
        int pB[3];
#pragma unroll
        for (int d = 0; d < 3; ++d) {
            const int dx = d - 1;
            pB[d] = bb + ((wc * 66 + 1 + dx + l15) << 5)
                  + ((l4 ^ (((l15 + dx) >> 1) & 3)) << 3);
        }

#pragma unroll
        for (int t = 0; t < 9; ++t) {
            const int tap = (t + OFF) % 9;          // compile-time
            // depth-1 W pipeline: consume na, prefetch seq[t+1]
            bf16x8 ca0 = na0, ca1 = na1, ca2 = na2, ca3 = na3;
            const short* wp2 = (t < 8) ? (wcur + ((t + 1 + OFF) % 9) * 2048)
                                       : (wnxt + OFF * 2048);
            na0 = *(const bf16x8*)(wp2);
            na1 = *(const bf16x8*)(wp2 + 512);
            na2 = *(const bf16x8*)(wp2 + 1024);
            na3 = *(const bf16x8*)(wp2 + 1536);

            const int p0 = pB[tap % 3] + (tap / 3) * 2112;
            bf16x8 b0 = *(const bf16x8*)&Xs[p0];
            bf16x8 b1 = *(const bf16x8*)&Xs[p0 + 512];
            bf16x8 b2 = *(const bf16x8*)&Xs[p0 + 1024];
            bf16x8 b3 = *(const bf16x8*)&Xs[p0 + 1536];

            __builtin_amdgcn_s_setprio(1);
            acc[0][0] = __builtin_amdgcn_mfma_f32_16x16x32_bf16(ca0, b0, acc[0][0], 0, 0, 0);
            acc[1][0] = __builtin_amdgcn_mfma_f32_16x16x32_bf16(ca1, b0, acc[1][0], 0, 0, 0);
            acc[2][0] = __builtin_amdgcn_mfma_f32_16x16x32_bf16(ca2, b0, acc[2][0], 0, 0, 0);
            acc[3][0] = __builtin_amdgcn_mfma_f32_16x16x32_bf16(ca3, b0, acc[3][0], 0, 0, 0);
            acc[0][1] = __builtin_amdgcn_mfma_f32_16x16x32_bf16(ca0, b1, acc[0][1], 0, 0, 0);
            acc[1][1] = __builtin_amdgcn_mfma_f32_16x16x32_bf16(ca1, b1, acc[1][1], 0, 0, 0);
            acc[2][1] = __builtin_amdgcn_mfma_f32_16x16x32_bf16(ca2, b1, acc[2][1], 0, 0, 0);
            acc[3][1] = __builtin_amdgcn_mfma_f32_16x16x32_bf16(ca3, b1, acc[3][1], 0, 0, 0);
            acc[0][2] = __builtin_amdgcn_mfma_f32_16x16x32_bf16(ca0, b2, acc[0][2], 0, 0, 0);
            acc[1][2] = __builtin_amdgcn_mfma_f32_16x16x32_bf16(ca1, b2, acc[1][2], 0, 0, 0);
            acc[2][2] = __builtin_amdgcn_mfma_f32_16x16x32_bf16(ca2, b2, acc[2][2], 0, 0, 0);
            acc[3][2] = __builtin_amdgcn_mfma_f32_16x16x32_bf16(ca3, b2, acc[3][2], 0, 0, 0);
            acc[0][3] = __builtin_amdgcn_mfma_f32_16x16x32_bf16(ca0, b3, acc[0][3], 0, 0, 0);
            acc[1][3] = __builtin_amdgcn_mfma_f32_16x16x32_bf16(ca1, b3, acc[1][3], 0, 0, 0);
            acc[2][3] = __builtin_amdgcn_mfma_f32_16x16x32_bf16(ca2, b3, acc[2][3], 0, 0, 0);
            acc[3][3] = __builtin_amdgcn_mfma_f32_16x16x32_bf16(ca3, b3, acc[3][3], 0, 0, 0);
            __builtin_amdgcn_s_setprio(0);
        }
    }

    // ---- epilogue: C/D layout col=lane&15 (pixel), row=(lane>>4)*4+r (oc) ----
#pragma unroll
    for (int m = 0; m < 4; ++m)
#pragma unroll
        for (int nn = 0; nn < 4; ++nn) {
            const int oc = (wr << 6) + (m << 4) + (l4 << 2);
            const int p  = (wc << 6) + (nn << 4) + l15;
            float* dst = outg + ((size_t)oc << 12) + p;
#pragma unroll
            for (int r = 0; r < 4; ++r) dst[(size_t)r << 12] = acc[m][nn][r];
        }
}

__global__ __launch_bounds__(256, 3) void k_conv(const short* __restrict__ xb,
                                                 const short* __restrict__ wmod,
                                                 float* __restrict__ out) {
    __shared__ __align__(16) short Xs[2 * 8448];   // 33792 B

    const int tid  = threadIdx.x;
    const int lane = tid & 63;
    const int wv   = tid >> 6;
    const int wr   = wv >> 1, wc = wv & 1;
    const int l15  = lane & 15;
    const int l4   = lane >> 4;
    const int ocb  = blockIdx.x >> 5, rowb = blockIdx.x & 31;
    const int g    = blockIdx.y, nb = blockIdx.z;
    const int y0   = rowb << 1;

    const short* xbg = xb + ((size_t)((nb * 4 + g) * 64) << 15);
    const short* wg  = wmod + ((size_t)((g * 4 + ocb) * 2 + wr)) * 294912;
    float* outg = out + (((size_t)(nb * 2048 + (g << 9) + ocb * 128)) << 12) + (rowb << 7);

    // staging: this wave stages image row gy = y0-1+wv
    const int gy = y0 - 1 + wv;
    const bool srow = (gy >= 0 && gy <= 63);
    const short* xsrc = xbg + ((size_t)(srow ? gy : 0) << 15) + (lane << 3);
    short* xdst0 = Xs + ((wv * 66 + 1) << 5);

    const short* wl = wg + (lane << 3);   // per-lane W base

    // zero both buffers (pad slots + out-of-range halo rows stay 0 forever)
    for (int i = tid; i < 4224; i += 256) ((u64*)Xs)[i] = 0ull;

    // co-resident blocks are spaced 256 in linear id -> (linear>>8)&1
    // alternates among them; rotation is block-uniform (no divergence).
    const int linear = blockIdx.x + (blockIdx.y << 7) + (blockIdx.z << 9);
    if (((linear >> 8) & 1) == 0)
        conv_main<0>(Xs, xsrc, xdst0, srow, wl, outg, wc, wr, l15, l4);
    else
        conv_main<4>(Xs, xsrc, xdst0, srow, wl, outg, wc, wr, l15, l4);
}

extern "C" void kernel_launch(void* const* d_in, const int* in_sizes, int n_in,
                              void* d_out, int out_size, void* d_ws, size_t ws_size,
                              hipStream_t stream) {
    const float* x      = (const float*)d_in[0];
    const float* style  = (const float*)d_in[1];
    const float* weight = (const float*)d_in[2];
    const float* demod  = (const float*)d_in[3];
    const float* mod_w  = (const float*)d_in[4];
    const float* mod_b  = (const float*)d_in[5];
    float* out = (float*)d_out;

    float* s_ws = (float*)d_ws;                           // 8 KB
    short* wmod = (short*)((char*)d_ws + 8192);           // 18.9 MB
    short* xbuf = (short*)((char*)d_ws + 8192 + 18874368);// 67.1 MB (total ~86 MB)

    hipLaunchKernelGGL(k_style, dim3(8), dim3(256), 0, stream, style, mod_w, mod_b, s_ws);
    hipLaunchKernelGGL(k_wmod, dim3(512), dim3(256), 0, stream, weight, demod, s_ws, wmod);
    hipLaunchKernelGGL(k_xcast, dim3(16384), dim3(256), 0, stream, x, xbuf);
    hipLaunchKernelGGL(k_conv, dim3(128, 4, 4), dim3(256), 0, stream, xbuf, wmod, out);
}